// Round 16
// baseline (431.623 us; speedup 1.0000x reference)
//
#include <hip/hip_runtime.h>

#define S_LEN 2048
#define DMODEL 2048
#define NH 32
#define NKV 8
#define HD 64
#define FFN_DIM 8192

typedef __attribute__((ext_vector_type(4))) float f32x4;
typedef __attribute__((ext_vector_type(16))) float f32x16;
typedef __attribute__((ext_vector_type(8))) short bf16x8;

#define MFMA(a, b, c) __builtin_amdgcn_mfma_f32_16x16x32_bf16(a, b, c, 0, 0, 0)
#define MFMA32(a, b, c) __builtin_amdgcn_mfma_f32_32x32x16_bf16(a, b, c, 0, 0, 0)

__device__ __forceinline__ ushort f2bf(float f) {
  unsigned u = __float_as_uint(f);
  unsigned r = (u + 0x7fffu + ((u >> 16) & 1u)) >> 16;
  return (ushort)r;
}
__device__ __forceinline__ float bf2f(ushort s) {
  return __uint_as_float(((unsigned)s) << 16);
}
__device__ __forceinline__ unsigned cvtpk(float a, float b) {
  unsigned r;
  asm("v_cvt_pk_bf16_f32 %0, %1, %2" : "=v"(r) : "v"(a), "v"(b));
  return r;
}

__device__ __forceinline__ void gload16(const void* g, void* l) {
  __builtin_amdgcn_global_load_lds(
      (const __attribute__((address_space(1))) void*)g,
      (__attribute__((address_space(3))) void*)l, 16, 0, 0);
}

__device__ __forceinline__ void cvt_row8(const float* src, ushort* dst,
                                         int i) {
  f32x4 a = *(const f32x4*)(src + i);
  f32x4 b = *(const f32x4*)(src + i + 4);
  bf16x8 r;
#pragma unroll
  for (int j = 0; j < 4; j++) r[j] = (short)f2bf(a[j]);
#pragma unroll
  for (int j = 0; j < 4; j++) r[4 + j] = (short)f2bf(b[j]);
  *(bf16x8*)(dst + i) = r;
}

// ======== pre_k: rmsnorm1 | cvt_qkv | bias3 (block-specialized) ========
__global__ __launch_bounds__(256) void pre_k(
    const float* __restrict__ hidden, const float* __restrict__ ln1,
    ushort* __restrict__ x1, const float* __restrict__ wq,
    const float* __restrict__ wk, const float* __restrict__ wv,
    ushort* __restrict__ cw, const float* __restrict__ bq,
    const float* __restrict__ bk, const float* __restrict__ bv,
    float* __restrict__ bqkv) {
  const int b = blockIdx.x;
  const int tid = threadIdx.x;
  if (b < 2048) {
    const float* x = hidden + (size_t)b * DMODEL;
    f32x4 v0 = *(const f32x4*)(x + tid * 8);
    f32x4 v1 = *(const f32x4*)(x + tid * 8 + 4);
    float ss = v0[0] * v0[0] + v0[1] * v0[1] + v0[2] * v0[2] + v0[3] * v0[3] +
               v1[0] * v1[0] + v1[1] * v1[1] + v1[2] * v1[2] + v1[3] * v1[3];
#pragma unroll
    for (int off = 32; off; off >>= 1) ss += __shfl_xor(ss, off, 64);
    __shared__ float red[4];
    if ((tid & 63) == 0) red[tid >> 6] = ss;
    __syncthreads();
    float tot = red[0] + red[1] + red[2] + red[3];
    float inv = rsqrtf(tot * (1.f / DMODEL) + 1e-5f);
#pragma unroll
    for (int i = 0; i < 8; i++) {
      int c = tid * 8 + i;
      float val = (i < 4) ? v0[i] : v1[i - 4];
      x1[(size_t)b * DMODEL + c] = f2bf(ln1[c] * val * inv);
    }
  } else if (b < 5120) {
    int row = b - 2048;
    const float* src;
    if (row < 2048) src = wq + (size_t)row * DMODEL;
    else if (row < 2560) src = wk + (size_t)(row - 2048) * DMODEL;
    else src = wv + (size_t)(row - 2560) * DMODEL;
    cvt_row8(src, cw + (size_t)row * DMODEL, tid * 8);
  } else {
    int i = (b - 5120) * 256 + tid;
    float v;
    if (i < 2048) v = bq[i];
    else if (i < 2560) v = bk[i - 2048];
    else v = bv[i - 2560];
    bqkv[i] = v;
  }
}

// ---------------- standalone conversions (fallback path) ----------------
__global__ __launch_bounds__(256) void cvt_k(const float* __restrict__ in,
                                             ushort* __restrict__ out) {
  int i = blockIdx.x * 256 + threadIdx.x;
  f32x4 a = ((const f32x4*)in)[i * 2];
  f32x4 b = ((const f32x4*)in)[i * 2 + 1];
  bf16x8 r;
#pragma unroll
  for (int j = 0; j < 4; j++) r[j] = (short)f2bf(a[j]);
#pragma unroll
  for (int j = 0; j < 4; j++) r[4 + j] = (short)f2bf(b[j]);
  ((bf16x8*)out)[i] = r;
}

__global__ __launch_bounds__(256) void cvt_w13_k(const float* __restrict__ w1,
                                                 const float* __restrict__ w3,
                                                 ushort* __restrict__ dst) {
  int r = blockIdx.x;
  int nb = r >> 8, i5 = r & 255;
  int wn = i5 >> 6, nf = (i5 >> 4) & 3, e = i5 & 15;
  int L = nb * 128 + wn * 32 + (nf >> 1) * 16 + e;
  const float* src = ((nf & 1) ? w3 : w1) + (size_t)L * DMODEL;
  cvt_row8(src, dst + (size_t)r * DMODEL, threadIdx.x * 8);
}

// ======== 128x128 GEMM (R10 core, correctness-proven): BK=64, 4 waves ======
__global__ __launch_bounds__(256) void gemm128(
    const ushort* __restrict__ A, int lda, const ushort* __restrict__ B,
    int ldb, ushort* __restrict__ outb, int ldc, int K, int kspan,
    long long opart) {
  __shared__ __align__(16) ushort lds[16384];
  const int tid = threadIdx.x;
  const int l = tid & 63, w = tid >> 6;
  const int g = l >> 4, r16 = l & 15;
  const int wm = w >> 1, wn = w & 1;

  int nwg = gridDim.x * gridDim.y;
  int bid = blockIdx.y * gridDim.x + blockIdx.x;
  bid = (bid & 7) * (nwg >> 3) + (bid >> 3);  // XCD swizzle (nwg%8==0)
  const int m0 = (bid % gridDim.x) * 128;
  const int n0 = (bid / gridDim.x) * 128;
  const int z = blockIdx.z;

  const ushort* Ag = A + (size_t)z * kspan + (size_t)m0 * lda;
  const ushort* Bg = B + (size_t)z * kspan + (size_t)n0 * ldb;
  ushort* outbz = outb + (size_t)z * opart;

  const int NT = K >> 6;

  const int stgRow = w * 8 + (l >> 3);
  const int stgCol = ((l & 7) ^ (l >> 3)) * 8;
  const int xa = (r16 & 7) << 4;
  const int c0 = ((g * 16) ^ xa) >> 1;
  const int c1 = c0 ^ 32;
  const ushort* pA0 = lds + (wm * 64 + r16) * 64 + c0;
  const ushort* pA1 = lds + (wm * 64 + r16) * 64 + c1;
  const ushort* pB0 = lds + 8192 + (wn * 64 + r16) * 64 + c0;
  const ushort* pB1 = lds + 8192 + (wn * 64 + r16) * 64 + c1;

  f32x4 acc[4][4];
#pragma unroll
  for (int i = 0; i < 4; i++)
#pragma unroll
    for (int j = 0; j < 4; j++) acc[i][j] = (f32x4){0, 0, 0, 0};

  for (int t = 0; t < NT; ++t) {
#pragma unroll
    for (int p = 0; p < 4; p++) {
      const int row = p * 32 + stgRow;
      gload16(Ag + (size_t)row * lda + t * 64 + stgCol,
              lds + (p * 32 + w * 8) * 64);
      gload16(Bg + (size_t)row * ldb + t * 64 + stgCol,
              lds + 8192 + (p * 32 + w * 8) * 64);
    }
    __syncthreads();
    bf16x8 Ar[8], Br[8];
#pragma unroll
    for (int mt = 0; mt < 4; mt++) {
      Ar[2 * mt] = *(const bf16x8*)(pA0 + mt * 1024);
      Ar[2 * mt + 1] = *(const bf16x8*)(pA1 + mt * 1024);
    }
#pragma unroll
    for (int nt = 0; nt < 4; nt++) {
      Br[2 * nt] = *(const bf16x8*)(pB0 + nt * 1024);
      Br[2 * nt + 1] = *(const bf16x8*)(pB1 + nt * 1024);
    }
#pragma unroll
    for (int kk = 0; kk < 2; kk++)
#pragma unroll
      for (int mt = 0; mt < 4; mt++)
#pragma unroll
        for (int nt = 0; nt < 4; nt++)
          acc[mt][nt] = MFMA(Ar[2 * mt + kk], Br[2 * nt + kk], acc[mt][nt]);
    __syncthreads();
  }

#pragma unroll
  for (int mf = 0; mf < 4; mf++)
#pragma unroll
    for (int nf = 0; nf < 4; nf++) {
      const int n = n0 + wn * 64 + nf * 16 + r16;
#pragma unroll
      for (int reg = 0; reg < 4; reg++) {
        const int m = m0 + wm * 64 + mf * 16 + g * 4 + reg;
        outbz[(size_t)m * ldc + n] = f2bf(acc[mf][nf][reg]);
      }
    }
}

// ======== 256x256 8-phase GEMM (R9 core) — w1w3 only ========
enum { EPI_PART = 0, EPI_SILU2 = 1 };

#define QUAD(AS, BS, MROW, NCOL)                                     \
  _Pragma("unroll") for (int kk_ = 0; kk_ < 2; kk_++)                \
  _Pragma("unroll") for (int mf_ = 0; mf_ < 4; mf_++)                \
  _Pragma("unroll") for (int nf_ = 0; nf_ < 2; nf_++)                \
      acc[(MROW) + mf_][(NCOL) + nf_] =                              \
          MFMA(AS[2 * mf_ + kk_], BS[2 * nf_ + kk_],                 \
               acc[(MROW) + mf_][(NCOL) + nf_]);

#define PHASE_MID                                    \
  __builtin_amdgcn_sched_barrier(0);                 \
  __builtin_amdgcn_s_barrier();                      \
  asm volatile("s_waitcnt lgkmcnt(0)" ::: "memory"); \
  __builtin_amdgcn_sched_barrier(0);                 \
  __builtin_amdgcn_s_setprio(1);

#define PHASE_CLOSE                                  \
  __builtin_amdgcn_s_setprio(0);                     \
  __builtin_amdgcn_sched_barrier(0);                 \
  __builtin_amdgcn_s_barrier();

#define RD_A(PA0, PA1, J0)                           \
  _Pragma("unroll") for (int j_ = 0; j_ < 4; j_++) { \
    A_[2 * j_] = *(const bf16x8*)((PA0) + ((J0) + j_) * 1024);     \
    A_[2 * j_ + 1] = *(const bf16x8*)((PA1) + ((J0) + j_) * 1024); \
  }
#define RD_B(DST, PB0, PB1, J0)                      \
  _Pragma("unroll") for (int n_ = 0; n_ < 2; n_++) { \
    DST[2 * n_] = *(const bf16x8*)((PB0) + ((J0) + n_) * 1024);     \
    DST[2 * n_ + 1] = *(const bf16x8*)((PB1) + ((J0) + n_) * 1024); \
  }

template <int EPI>
__global__ __launch_bounds__(512, 2) void gemm256(
    const ushort* __restrict__ A, int lda, const ushort* __restrict__ B,
    int ldb, const float* __restrict__ b1v, const float* __restrict__ b3v,
    ushort* __restrict__ outb, int ldc, int K, int kspan, long long opart) {
  __shared__ __align__(16) ushort lds[65536];
  const int tid = threadIdx.x;
  const int l = tid & 63, w = tid >> 6;
  const int g = l >> 4, r16 = l & 15;
  const int wm = w >> 2, wn = w & 3;

  int nwg = gridDim.x * gridDim.y;
  int bid = blockIdx.y * gridDim.x + blockIdx.x;
  bid = (bid & 7) * (nwg >> 3) + (bid >> 3);
  const int m0 = (bid % gridDim.x) * 256;
  const int n0 = (bid / gridDim.x) * 256;
  const int z = blockIdx.z;

  const ushort* Ag = A + (size_t)z * kspan + (size_t)m0 * lda;
  const ushort* Bg = B + (size_t)z * kspan + (size_t)n0 * ldb;
  ushort* outbz = outb + (size_t)z * opart;

  const int NT = K >> 6, NI = NT >> 1;

  const int stgRow = w * 8 + (l >> 3);
  const int stgCol = ((l & 7) ^ (l >> 3)) * 8;

  const int xa = (r16 & 7) << 4;
  const int c0 = ((g * 16) ^ xa) >> 1;
  const int c1 = c0 ^ 32;
  const int aslot = wm ? 24576 : 8192;
  const int bslot = ((wn >> 1) ? 16384 : 0) + (wn & 1) * 4096;
  const ushort* pA0b0 = lds + aslot + r16 * 64 + c0;
  const ushort* pA1b0 = lds + aslot + r16 * 64 + c1;
  const ushort* pA0b1 = pA0b0 + 32768;
  const ushort* pA1b1 = pA1b0 + 32768;
  const ushort* pB0b0 = lds + bslot + r16 * 64 + c0;
  const ushort* pB1b0 = lds + bslot + r16 * 64 + c1;
  const ushort* pB0b1 = pB0b0 + 32768;
  const ushort* pB1b1 = pB1b0 + 32768;

  f32x4 acc[8][4];
#pragma unroll
  for (int i = 0; i < 8; i++)
#pragma unroll
    for (int j = 0; j < 4; j++) acc[i][j] = (f32x4){0, 0, 0, 0};

  auto stageA = [&](int slot, int tile, int hf) {
    ushort* dst = lds + ((tile & 1) * 32768 + slot * 8192 + w * 512);
    const ushort* src =
        Ag + (size_t)(hf * 128 + stgRow) * lda + tile * 64 + stgCol;
    gload16(src, dst);
    gload16(src + (size_t)64 * lda, dst + 4096);
  };
  auto stageB = [&](int slot, int tile, int hf) {
    ushort* dst = lds + ((tile & 1) * 32768 + slot * 8192 + w * 512);
    const ushort* src =
        Bg + (size_t)(hf * 128 + stgRow) * ldb + tile * 64 + stgCol;
    gload16(src, dst);
    gload16(src + (size_t)64 * ldb, dst + 4096);
  };

  stageB(0, 0, 0);
  stageB(2, 0, 1);
  stageA(1, 0, 0);
  stageA(3, 0, 1);
  stageB(0, 1, 0);
  stageB(2, 1, 1);
  asm volatile("s_waitcnt vmcnt(4)" ::: "memory");
  __builtin_amdgcn_s_barrier();

  bf16x8 A_[8], Blo[4], Bhi[4];

  for (int i = 0; i < NI; ++i) {
    const int ta = 2 * i, tb = 2 * i + 1;
    const bool st = (ta + 2 < NT);
    RD_A(pA0b0, pA1b0, 0);
    RD_B(Blo, pB0b0, pB1b0, 0);
    stageA(1, tb, 0);
    asm volatile("s_waitcnt lgkmcnt(8)" ::: "memory");
    PHASE_MID; QUAD(A_, Blo, 0, 0); PHASE_CLOSE;
    RD_B(Bhi, pB0b0, pB1b0, 2);
    stageA(3, tb, 1);
    PHASE_MID; QUAD(A_, Bhi, 0, 2); PHASE_CLOSE;
    RD_A(pA0b0, pA1b0, 4);
    if (st) stageB(0, ta + 2, 0);
    PHASE_MID; QUAD(A_, Bhi, 4, 2); PHASE_CLOSE;
    if (st) stageB(2, ta + 2, 1);
    PHASE_MID; QUAD(A_, Blo, 4, 0);
    __builtin_amdgcn_s_setprio(0);
    __builtin_amdgcn_sched_barrier(0);
    if (st) {
      asm volatile("s_waitcnt vmcnt(4)" ::: "memory");
    } else {
      asm volatile("s_waitcnt vmcnt(0)" ::: "memory");
    }
    __builtin_amdgcn_s_barrier();
    RD_A(pA0b1, pA1b1, 0);
    RD_B(Blo, pB0b1, pB1b1, 0);
    if (st) stageA(1, ta + 2, 0);
    asm volatile("s_waitcnt lgkmcnt(8)" ::: "memory");
    PHASE_MID; QUAD(A_, Blo, 0, 0); PHASE_CLOSE;
    RD_B(Bhi, pB0b1, pB1b1, 2);
    if (st) stageA(3, ta + 2, 1);
    PHASE_MID; QUAD(A_, Bhi, 0, 2); PHASE_CLOSE;
    RD_A(pA0b1, pA1b1, 4);
    if (st) stageB(0, tb + 2, 0);
    PHASE_MID; QUAD(A_, Bhi, 4, 2); PHASE_CLOSE;
    if (st) stageB(2, tb + 2, 1);
    PHASE_MID; QUAD(A_, Blo, 4, 0);
    __builtin_amdgcn_s_setprio(0);
    __builtin_amdgcn_sched_barrier(0);
    asm volatile("s_waitcnt vmcnt(4)" ::: "memory");
    __builtin_amdgcn_s_barrier();
  }

  if constexpr (EPI == EPI_PART) {
#pragma unroll
    for (int mf = 0; mf < 8; mf++)
#pragma unroll
      for (int nf = 0; nf < 4; nf++) {
        const int n = n0 + wn * 64 + nf * 16 + r16;
#pragma unroll
        for (int reg = 0; reg < 4; reg++) {
          const int m = m0 + wm * 128 + mf * 16 + g * 4 + reg;
          outbz[(size_t)m * ldc + n] = f2bf(acc[mf][nf][reg]);
        }
      }
  } else {
#pragma unroll
    for (int mf = 0; mf < 8; mf++)
#pragma unroll
      for (int p = 0; p < 2; p++) {
        const int L = (n0 >> 1) + wn * 32 + p * 16 + r16;
        const float bb1 = b1v[L], bb3 = b3v[L];
#pragma unroll
        for (int reg = 0; reg < 4; reg++) {
          const int m = m0 + wm * 128 + mf * 16 + g * 4 + reg;
          float h1 = acc[mf][2 * p][reg] + bb1;
          float h3 = acc[mf][2 * p + 1][reg] + bb3;
          float sv = h1 / (1.f + __expf(-h1));
          outbz[(size_t)m * ldc + L] = f2bf(sv * h3);
        }
      }
  }
}

// ---------------- fused QKV reduce + bias + RoPE ----------------
template <int NZ>
__global__ __launch_bounds__(384) void reduceQ_rope_k(
    const ushort* __restrict__ part, const float* __restrict__ bias,
    const float* __restrict__ cs, const float* __restrict__ sn,
    ushort* __restrict__ qkv) {
  __shared__ float row[3072];
  const int r = blockIdx.x;
  const int col = threadIdx.x * 8;
  const long long ps = (long long)S_LEN * 3072;
  float s[8];
#pragma unroll
  for (int j = 0; j < 8; j++) s[j] = bias[col + j];
#pragma unroll
  for (int z = 0; z < NZ; z++) {
    bf16x8 v = *(const bf16x8*)(part + z * ps + (size_t)r * 3072 + col);
#pragma unroll
    for (int j = 0; j < 8; j++) s[j] += bf2f((ushort)v[j]);
  }
#pragma unroll
  for (int j = 0; j < 8; j++) row[col + j] = s[j];
  __syncthreads();
  ushort o[8];
  if (col < 2560) {
    const float* c = cs + r * HD + (col & 63);
    const float* si = sn + r * HD + (col & 63);
    const float sgn = (col & 32) ? 1.f : -1.f;
    const int pc = col ^ 32;
#pragma unroll
    for (int j = 0; j < 8; j++)
      o[j] = f2bf(s[j] * c[j] + sgn * row[pc + j] * si[j]);
  } else {
#pragma unroll
    for (int j = 0; j < 8; j++) o[j] = f2bf(s[j]);
  }
  bf16x8 rr;
#pragma unroll
  for (int j = 0; j < 8; j++) rr[j] = (short)o[j];
  *(bf16x8*)(qkv + (size_t)r * 3072 + col) = rr;
}

// ------- fused O-proj reduce + bias + resid -> out(f32) + RMSNorm -> x2 ----
template <int NZ>
__global__ __launch_bounds__(256) void reduceO_rms_k(
    const ushort* __restrict__ part, const float* __restrict__ bias,
    const float* __restrict__ resid, const float* __restrict__ lnw,
    float* __restrict__ outf, ushort* __restrict__ x2) {
  const int r = blockIdx.x;
  const int tid = threadIdx.x;
  const int col = tid * 8;
  const long long ps = (long long)S_LEN * DMODEL;
  float s[8];
#pragma unroll
  for (int j = 0; j < 8; j++) s[j] = bias[col + j] + resid[(size_t)r * DMODEL + col + j];
#pragma unroll
  for (int z = 0; z < NZ; z++) {
    bf16x8 v = *(const bf16x8*)(part + z * ps + (size_t)r * DMODEL + col);
#pragma unroll
    for (int j = 0; j < 8; j++) s[j] += bf2f((ushort)v[j]);
  }
  float ss = 0.f;
#pragma unroll
  for (int j = 0; j < 8; j++) ss += s[j] * s[j];
#pragma unroll
  for (int off = 32; off; off >>= 1) ss += __shfl_xor(ss, off, 64);
  __shared__ float red[4];
  if ((tid & 63) == 0) red[tid >> 6] = ss;
  f32x4 o0, o1;
#pragma unroll
  for (int j = 0; j < 4; j++) { o0[j] = s[j]; o1[j] = s[4 + j]; }
  *(f32x4*)(outf + (size_t)r * DMODEL + col) = o0;
  *(f32x4*)(outf + (size_t)r * DMODEL + col + 4) = o1;
  __syncthreads();
  float tot = red[0] + red[1] + red[2] + red[3];
  float inv = rsqrtf(tot * (1.f / DMODEL) + 1e-5f);
  bf16x8 rr;
#pragma unroll
  for (int j = 0; j < 8; j++) rr[j] = (short)f2bf(lnw[col + j] * s[j] * inv);
  *(bf16x8*)(x2 + (size_t)r * DMODEL + col) = rr;
}

// ---------------- w2 reduce (f32 out + resid) ----------------
template <int NZ>
__global__ __launch_bounds__(256) void reduceW_k(
    const ushort* __restrict__ part, const float* __restrict__ bias,
    float* __restrict__ out) {
  long long i = (long long)(blockIdx.x * 256 + threadIdx.x) * 8;
  int col = (int)(i % DMODEL);
  const long long ps = (long long)S_LEN * DMODEL;
  float s[8];
#pragma unroll
  for (int j = 0; j < 8; j++) s[j] = bias[col + j] + out[i + j];
#pragma unroll
  for (int z = 0; z < NZ; z++) {
    bf16x8 v = *(const bf16x8*)(part + z * ps + i);
#pragma unroll
    for (int j = 0; j < 8; j++) s[j] += bf2f((ushort)v[j]);
  }
#pragma unroll
  for (int j = 0; j < 8; j++) out[i + j] = s[j];
}

// ======== Flash attention (QBLK=64, 128 threads) + cvt blocks ========
__global__ __launch_bounds__(128, 3) void flash2_k(
    const ushort* __restrict__ qkv, ushort* __restrict__ att, int nFlash,
    int nCvtTasks, const float* __restrict__ wo, const float* __restrict__ w1,
    const float* __restrict__ w3, const float* __restrict__ w2s,
    ushort* __restrict__ cwA, ushort* __restrict__ cwB) {
  if ((int)blockIdx.x >= nFlash) {
    const int cb = blockIdx.x - nFlash;
    const int NC = gridDim.x - nFlash;
    const int i = threadIdx.x * 8;
    for (int t = cb; t < nCvtTasks; t += NC) {
      const float* src;
      ushort* dst;
      if (t < 2048) {
        src = wo + (size_t)t * DMODEL;
        dst = cwB + (size_t)t * DMODEL;
      } else if (t < 18432) {
        int r = t - 2048;
        int nb = r >> 8, i5 = r & 255;
        int wn = i5 >> 6, nf = (i5 >> 4) & 3, e = i5 & 15;
        int L = nb * 128 + wn * 32 + (nf >> 1) * 16 + e;
        src = ((nf & 1) ? w3 : w1) + (size_t)L * DMODEL;
        dst = cwA + (size_t)r * DMODEL;
      } else {
        int r = t - 18432;
        src = w2s + (size_t)r * 2048;
        dst = cwB + (size_t)2048 * DMODEL + (size_t)r * 2048;
      }
      cvt_row8(src, dst, i);
      cvt_row8(src, dst, i + 1024);
    }
    return;
  }
  const int bid = blockIdx.x;
  const int head = (bid >> 5) & 31;
  const int rmap = bid & 31;
  const int qb = (bid & 512) ? (31 - rmap) : rmap;
  const int kvh = head >> 2;
  const int tid = threadIdx.x;
  const int w = tid >> 6, l = tid & 63;
  const int h = l >> 5, q31 = l & 31;
  const int qw = qb * 64 + w * 32;
  const int qrow = qw + q31;

  __shared__ __align__(16) ushort lds[2][8192];

  bf16x8 qreg[4];
  {
    const ushort* qp = qkv + (size_t)qrow * 3072 + head * HD;
#pragma unroll
    for (int s = 0; s < 4; s++)
      qreg[s] = *(const bf16x8*)(qp + s * 16 + h * 8);
  }

  f32x16 oacc[2];
#pragma unroll
  for (int i = 0; i < 16; i++) { oacc[0][i] = 0.f; oacc[1][i] = 0.f; }
  float mreg = -1e30f, lsum = 0.f;

  const int nt = qb + 1;

  const int skv = tid >> 1;
  const int sc4 = (tid & 1) * 4;
  const int vkv = tid & 63;
  const int vd0 = (tid >> 6) * 32;

  const ushort* kg_base = qkv + DMODEL + kvh * HD;

  bf16x8 kr[4], vr[4];
  auto loadTile = [&](int jb) {
    const ushort* kg = kg_base + (size_t)jb * 64 * 3072;
#pragma unroll
    for (int c = 0; c < 4; c++)
      kr[c] = *(const bf16x8*)(kg + (size_t)skv * 3072 + (sc4 + c) * 8);
    const ushort* vg = kg + 512;
#pragma unroll
    for (int c = 0; c < 4; c++)
      vr[c] = *(const bf16x8*)(vg + (size_t)vkv * 3072 + vd0 + c * 8);
  };
  auto writeTile = [&](int b) {
    ushort* kb = lds[b];
#pragma unroll
    for (int c = 0; c < 4; c++)
      *(bf16x8*)(kb + skv * 64 + (((sc4 + c) ^ (skv & 7)) * 8)) = kr[c];
    ushort* vb = lds[b] + 4096;
#pragma unroll
    for (int c = 0; c < 4; c++)
#pragma unroll
      for (int i = 0; i < 8; i++) {
        int d = vd0 + c * 8 + i;
        vb[d * 64 + (((vkv >> 3) ^ (d & 7)) * 8) + (vkv & 7)] = (ushort)vr[c][i];
      }
  };

  loadTile(0);
  for (int jb = 0; jb < nt; ++jb) {
    const int b = jb & 1;
    writeTile(b);
    __syncthreads();
    if (jb + 1 < nt) loadTile(jb + 1);

    if (jb * 64 <= qw + 31) {
      const ushort* Kb = lds[b];
      const ushort* Vb = lds[b] + 4096;

      f32x16 sacc[2];
#pragma unroll
      for (int i = 0; i < 16; i++) { sacc[0][i] = 0.f; sacc[1][i] = 0.f; }
#pragma unroll
      for (int c = 0; c < 2; c++) {
        const int kvr = c * 32 + q31;
        const ushort* kp = Kb + kvr * 64;
        const int kx = kvr & 7;
#pragma unroll
        for (int s = 0; s < 4; s++) {
          bf16x8 kf = *(const bf16x8*)(kp + ((2 * s + h) ^ kx) * 8);
          sacc[c] = MFMA32(kf, qreg[s], sacc[c]);
        }
      }

      const bool diag = (jb * 64 + 63 > qw);
      if (diag) {
#pragma unroll
        for (int c = 0; c < 2; c++)
#pragma unroll
          for (int rg = 0; rg < 16; rg++) {
            int kvg = jb * 64 + c * 32 + (rg & 3) + 8 * (rg >> 2) + 4 * h;
            if (kvg > qrow) sacc[c][rg] = -1e30f;
          }
      }
      float tmax = sacc[0][0];
#pragma unroll
      for (int rg = 1; rg < 16; rg++) tmax = fmaxf(tmax, sacc[0][rg]);
#pragma unroll
      for (int rg = 0; rg < 16; rg++) tmax = fmaxf(tmax, sacc[1][rg]);
      tmax = fmaxf(tmax, __shfl_xor(tmax, 32));
      const float mn = fmaxf(mreg, tmax);
      const float resc = __expf((mreg - mn) * 0.125f);
      mreg = mn;
      float rsum = 0.f;
#pragma unroll
      for (int c = 0; c < 2; c++)
#pragma unroll
        for (int rg = 0; rg < 16; rg++) {
          float pv = __expf((sacc[c][rg] - mn) * 0.125f);
          sacc[c][rg] = pv;
          rsum += pv;
        }
      rsum += __shfl_xor(rsum, 32);
      lsum = lsum * resc + rsum;
      oacc[0] *= resc;
      oacc[1] *= resc;

      unsigned pw_[2][4][2];
#pragma unroll
      for (int c = 0; c < 2; c++)
#pragma unroll
        for (int rr = 0; rr < 4; rr++) {
          pw_[c][rr][0] = cvtpk(sacc[c][4 * rr + 0], sacc[c][4 * rr + 1]);
          pw_[c][rr][1] = cvtpk(sacc[c][4 * rr + 2], sacc[c][4 * rr + 3]);
        }

#pragma unroll
      for (int s = 0; s < 4; s++) {
        const int c = s >> 1, base = (s & 1) * 2;
        unsigned k0 = h ? pw_[c][base + 1][0] : pw_[c][base][0];
        unsigned k1 = h ? pw_[c][base + 1][1] : pw_[c][base][1];
        unsigned s0 = h ? pw_[c][base][0] : pw_[c][base + 1][0];
        unsigned s1 = h ? pw_[c][base][1] : pw_[c][base + 1][1];
        unsigned t0 = __shfl_xor(s0, 32);
        unsigned t1 = __shfl_xor(s1, 32);
        union { unsigned u[4]; bf16x8 v; } pf;
        pf.u[0] = h ? t0 : k0;
        pf.u[1] = h ? t1 : k1;
        pf.u[2] = h ? k0 : t0;
        pf.u[3] = h ? k1 : t1;
#pragma unroll
        for (int dt = 0; dt < 2; dt++) {
          const int d = dt * 32 + q31;
          bf16x8 vf =
              *(const bf16x8*)(Vb + d * 64 + ((2 * s + h) ^ (d & 7)) * 8);
          oacc[dt] = MFMA32(vf, pf.v, oacc[dt]);
        }
      }
    }
  }

  const float inv = 1.f / lsum;
  ushort* op = att + (size_t)qrow * DMODEL + head * HD;
#pragma unroll
  for (int dt = 0; dt < 2; dt++)
#pragma unroll
    for (int rr = 0; rr < 4; rr++) {
      const int d0 = dt * 32 + 8 * rr + 4 * h;
      unsigned lo = cvtpk(oacc[dt][4 * rr + 0] * inv, oacc[dt][4 * rr + 1] * inv);
      unsigned hi = cvtpk(oacc[dt][4 * rr + 2] * inv, oacc[dt][4 * rr + 3] * inv);
      uint2 v2;
      v2.x = lo;
      v2.y = hi;
      *(uint2*)(op + d0) = v2;
    }
}

extern "C" void kernel_launch(void* const* d_in, const int* in_sizes, int n_in,
                              void* d_out, int out_size, void* d_ws,
                              size_t ws_size, hipStream_t stream) {
  (void)in_sizes; (void)n_in; (void)out_size;
  const float* hidden = (const float*)d_in[0];
  const float* cosb = (const float*)d_in[1];
  const float* sinb = (const float*)d_in[2];
  const float* wq = (const float*)d_in[4];
  const float* bq = (const float*)d_in[5];
  const float* wk = (const float*)d_in[6];
  const float* bk = (const float*)d_in[7];
  const float* wv = (const float*)d_in[8];
  const float* bv = (const float*)d_in[9];
  const float* wo = (const float*)d_in[10];
  const float* bo = (const float*)d_in[11];
  const float* ln1 = (const float*)d_in[12];
  const float* ln2 = (const float*)d_in[13];
  const float* w1 = (const float*)d_in[16];
  const float* b1 = (const float*)d_in[17];
  const float* w2 = (const float*)d_in[18];
  const float* b2 = (const float*)d_in[19];
  const float* w3 = (const float*)d_in[20];
  const float* b3 = (const float*)d_in[21];
  float* out = (float*)d_out;

  char* base = (char*)d_ws;
  char* ws = base;
  ushort* x1 = (ushort*)ws;   ws += (size_t)S_LEN * DMODEL * 2;
  ushort* qkv = (ushort*)ws;  ws += (size_t)S_LEN * 3072 * 2;
  ushort* att = (ushort*)ws;  ws += (size_t)S_LEN * DMODEL * 2;
  ushort* x2 = (ushort*)ws;   ws += (size_t)S_LEN * DMODEL * 2;
  ushort* hbuf = (ushort*)ws; ws += (size_t)S_LEN * FFN_DIM * 2;
  ushort* cwA = (ushort*)ws;  ws += (size_t)2 * FFN_DIM * DMODEL * 2;
  float* bqkv = (float*)ws;   ws += 4096 * 4;
  ushort* cwB = (ushort*)ws;
  const size_t cwB_bytes = (size_t)(2048 + 8192) * DMODEL * 2;
  const bool bigws = ((size_t)(ws - base) + cwB_bytes) <= ws_size;

  ushort* partQ = att;   // 12.6MB over att+x2 (dead pre-attention)
  ushort* partO = hbuf;  // 8.4MB == hbuf head (dead pre-FFN); x2 live
  ushort* partW = x1;    // 2x8.4MB over x1+qkv (dead at w2)

  // 1. rmsnorm1 + cvt_qkv + bias3
  pre_k<<<5132, 256, 0, stream>>>(hidden, ln1, x1, wq, wk, wv, cwA, bq, bk, bv,
                                  bqkv);

  // 2. QKV GEMM (128-tile, no split, 384 blocks) -> reduce(bias+RoPE) -> qkv
  gemm128<<<dim3(16, 24), 256, 0, stream>>>(x1, DMODEL, cwA, DMODEL, partQ,
                                            3072, DMODEL, 0, 0);
  reduceQ_rope_k<1><<<S_LEN, 384, 0, stream>>>(partQ, bqkv, cosb, sinb, qkv);

  const ushort *Bo, *B13, *B2;
  if (bigws) {
    // 3. Flash attention (1024 blocks) + 512 cvt blocks
    flash2_k<<<1024 + 512, 128, 0, stream>>>(qkv, att, 1024, 26624, wo, w1, w3,
                                             w2, cwA, cwB);
    Bo = cwB;
    B13 = cwA;
    B2 = cwB + (size_t)2048 * DMODEL;
  } else {
    flash2_k<<<1024, 128, 0, stream>>>(qkv, att, 1024, 0, wo, w1, w3, w2, cwA,
                                       cwA);
    Bo = cwA;
    B13 = cwA;
    B2 = cwA;
  }

  // 4. O-proj (128-tile, no split, 256 blocks) -> reduce+resid+RMSNorm2
  if (!bigws) cvt_k<<<(2048 * 2048) / 2048, 256, 0, stream>>>(wo, (ushort*)Bo);
  gemm128<<<dim3(16, 16), 256, 0, stream>>>(att, DMODEL, Bo, DMODEL, partO,
                                            DMODEL, DMODEL, 0, 0);
  reduceO_rms_k<1><<<S_LEN, 256, 0, stream>>>(partO, bo, hidden, ln2, out, x2);

  // 5. fused w1+w3 GEMM (256-tile) -> hbuf = silu(h1)*h3
  if (!bigws) cvt_w13_k<<<2 * FFN_DIM, 256, 0, stream>>>(w1, w3, (ushort*)B13);
  gemm256<EPI_SILU2><<<dim3(8, 64), 512, 0, stream>>>(
      x2, DMODEL, B13, DMODEL, b1, b3, hbuf, FFN_DIM, DMODEL, 0, 0);

  // 6. w2 (128-tile, split-K2, 512 blocks, K=4096) -> reduce -> out
  if (!bigws) cvt_k<<<(DMODEL * FFN_DIM) / 2048, 256, 0, stream>>>(w2, (ushort*)B2);
  gemm128<<<dim3(16, 16, 2), 256, 0, stream>>>(hbuf, FFN_DIM, B2, FFN_DIM,
                                               partW, DMODEL, 4096, 4096,
                                               (long long)S_LEN * DMODEL);
  reduceW_k<2><<<(S_LEN * DMODEL) / 2048, 256, 0, stream>>>(partW, b2, out);
}

// Round 17
// 376.498 us; speedup vs baseline: 1.1464x; 1.1464x over previous
//
#include <hip/hip_runtime.h>

#define S_LEN 2048
#define DMODEL 2048
#define NH 32
#define NKV 8
#define HD 64
#define FFN_DIM 8192

typedef __attribute__((ext_vector_type(4))) float f32x4;
typedef __attribute__((ext_vector_type(16))) float f32x16;
typedef __attribute__((ext_vector_type(8))) short bf16x8;

#define MFMA(a, b, c) __builtin_amdgcn_mfma_f32_16x16x32_bf16(a, b, c, 0, 0, 0)
#define MFMA32(a, b, c) __builtin_amdgcn_mfma_f32_32x32x16_bf16(a, b, c, 0, 0, 0)

__device__ __forceinline__ ushort f2bf(float f) {
  unsigned u = __float_as_uint(f);
  unsigned r = (u + 0x7fffu + ((u >> 16) & 1u)) >> 16;
  return (ushort)r;
}
__device__ __forceinline__ float bf2f(ushort s) {
  return __uint_as_float(((unsigned)s) << 16);
}
__device__ __forceinline__ unsigned cvtpk(float a, float b) {
  unsigned r;
  asm("v_cvt_pk_bf16_f32 %0, %1, %2" : "=v"(r) : "v"(a), "v"(b));
  return r;
}

__device__ __forceinline__ void gload16(const void* g, void* l) {
  __builtin_amdgcn_global_load_lds(
      (const __attribute__((address_space(1))) void*)g,
      (__attribute__((address_space(3))) void*)l, 16, 0, 0);
}

__device__ __forceinline__ void cvt_row8(const float* src, ushort* dst,
                                         int i) {
  f32x4 a = *(const f32x4*)(src + i);
  f32x4 b = *(const f32x4*)(src + i + 4);
  bf16x8 r;
#pragma unroll
  for (int j = 0; j < 4; j++) r[j] = (short)f2bf(a[j]);
#pragma unroll
  for (int j = 0; j < 4; j++) r[4 + j] = (short)f2bf(b[j]);
  *(bf16x8*)(dst + i) = r;
}

// ======== pre_k: rmsnorm1 | cvt_qkv | bias3 (block-specialized) ========
__global__ __launch_bounds__(256) void pre_k(
    const float* __restrict__ hidden, const float* __restrict__ ln1,
    ushort* __restrict__ x1, const float* __restrict__ wq,
    const float* __restrict__ wk, const float* __restrict__ wv,
    ushort* __restrict__ cw, const float* __restrict__ bq,
    const float* __restrict__ bk, const float* __restrict__ bv,
    float* __restrict__ bqkv) {
  const int b = blockIdx.x;
  const int tid = threadIdx.x;
  if (b < 2048) {
    const float* x = hidden + (size_t)b * DMODEL;
    f32x4 v0 = *(const f32x4*)(x + tid * 8);
    f32x4 v1 = *(const f32x4*)(x + tid * 8 + 4);
    float ss = v0[0] * v0[0] + v0[1] * v0[1] + v0[2] * v0[2] + v0[3] * v0[3] +
               v1[0] * v1[0] + v1[1] * v1[1] + v1[2] * v1[2] + v1[3] * v1[3];
#pragma unroll
    for (int off = 32; off; off >>= 1) ss += __shfl_xor(ss, off, 64);
    __shared__ float red[4];
    if ((tid & 63) == 0) red[tid >> 6] = ss;
    __syncthreads();
    float tot = red[0] + red[1] + red[2] + red[3];
    float inv = rsqrtf(tot * (1.f / DMODEL) + 1e-5f);
#pragma unroll
    for (int i = 0; i < 8; i++) {
      int c = tid * 8 + i;
      float val = (i < 4) ? v0[i] : v1[i - 4];
      x1[(size_t)b * DMODEL + c] = f2bf(ln1[c] * val * inv);
    }
  } else if (b < 5120) {
    int row = b - 2048;
    const float* src;
    if (row < 2048) src = wq + (size_t)row * DMODEL;
    else if (row < 2560) src = wk + (size_t)(row - 2048) * DMODEL;
    else src = wv + (size_t)(row - 2560) * DMODEL;
    cvt_row8(src, cw + (size_t)row * DMODEL, tid * 8);
  } else {
    int i = (b - 5120) * 256 + tid;
    float v;
    if (i < 2048) v = bq[i];
    else if (i < 2560) v = bk[i - 2048];
    else v = bv[i - 2560];
    bqkv[i] = v;
  }
}

// ---------------- standalone conversions (fallback path) ----------------
__global__ __launch_bounds__(256) void cvt_k(const float* __restrict__ in,
                                             ushort* __restrict__ out) {
  int i = blockIdx.x * 256 + threadIdx.x;
  f32x4 a = ((const f32x4*)in)[i * 2];
  f32x4 b = ((const f32x4*)in)[i * 2 + 1];
  bf16x8 r;
#pragma unroll
  for (int j = 0; j < 4; j++) r[j] = (short)f2bf(a[j]);
#pragma unroll
  for (int j = 0; j < 4; j++) r[4 + j] = (short)f2bf(b[j]);
  ((bf16x8*)out)[i] = r;
}

__global__ __launch_bounds__(256) void cvt_w13_k(const float* __restrict__ w1,
                                                 const float* __restrict__ w3,
                                                 ushort* __restrict__ dst) {
  int r = blockIdx.x;
  int nb = r >> 8, i5 = r & 255;
  int wn = i5 >> 6, nf = (i5 >> 4) & 3, e = i5 & 15;
  int L = nb * 128 + wn * 32 + (nf >> 1) * 16 + e;
  const float* src = ((nf & 1) ? w3 : w1) + (size_t)L * DMODEL;
  cvt_row8(src, dst + (size_t)r * DMODEL, threadIdx.x * 8);
}

// ======== 256x256 8-phase GEMM (R9 core) ========
enum { EPI_PART = 0, EPI_SILU2 = 1 };

#define QUAD(AS, BS, MROW, NCOL)                                     \
  _Pragma("unroll") for (int kk_ = 0; kk_ < 2; kk_++)                \
  _Pragma("unroll") for (int mf_ = 0; mf_ < 4; mf_++)                \
  _Pragma("unroll") for (int nf_ = 0; nf_ < 2; nf_++)                \
      acc[(MROW) + mf_][(NCOL) + nf_] =                              \
          MFMA(AS[2 * mf_ + kk_], BS[2 * nf_ + kk_],                 \
               acc[(MROW) + mf_][(NCOL) + nf_]);

#define PHASE_MID                                    \
  __builtin_amdgcn_sched_barrier(0);                 \
  __builtin_amdgcn_s_barrier();                      \
  asm volatile("s_waitcnt lgkmcnt(0)" ::: "memory"); \
  __builtin_amdgcn_sched_barrier(0);                 \
  __builtin_amdgcn_s_setprio(1);

#define PHASE_CLOSE                                  \
  __builtin_amdgcn_s_setprio(0);                     \
  __builtin_amdgcn_sched_barrier(0);                 \
  __builtin_amdgcn_s_barrier();

#define RD_A(PA0, PA1, J0)                           \
  _Pragma("unroll") for (int j_ = 0; j_ < 4; j_++) { \
    A_[2 * j_] = *(const bf16x8*)((PA0) + ((J0) + j_) * 1024);     \
    A_[2 * j_ + 1] = *(const bf16x8*)((PA1) + ((J0) + j_) * 1024); \
  }
#define RD_B(DST, PB0, PB1, J0)                      \
  _Pragma("unroll") for (int n_ = 0; n_ < 2; n_++) { \
    DST[2 * n_] = *(const bf16x8*)((PB0) + ((J0) + n_) * 1024);     \
    DST[2 * n_ + 1] = *(const bf16x8*)((PB1) + ((J0) + n_) * 1024); \
  }

template <int EPI>
__global__ __launch_bounds__(512, 2) void gemm256(
    const ushort* __restrict__ A, int lda, const ushort* __restrict__ B,
    int ldb, const float* __restrict__ b1v, const float* __restrict__ b3v,
    ushort* __restrict__ outb, int ldc, int K, int kspan, long long opart) {
  __shared__ __align__(16) ushort lds[65536];
  const int tid = threadIdx.x;
  const int l = tid & 63, w = tid >> 6;
  const int g = l >> 4, r16 = l & 15;
  const int wm = w >> 2, wn = w & 3;

  int nwg = gridDim.x * gridDim.y;
  int bid = blockIdx.y * gridDim.x + blockIdx.x;
  bid = (bid & 7) * (nwg >> 3) + (bid >> 3);  // XCD swizzle (nwg%8==0)
  const int m0 = (bid % gridDim.x) * 256;
  const int n0 = (bid / gridDim.x) * 256;
  const int z = blockIdx.z;

  const ushort* Ag = A + (size_t)z * kspan + (size_t)m0 * lda;
  const ushort* Bg = B + (size_t)z * kspan + (size_t)n0 * ldb;
  ushort* outbz = outb + (size_t)z * opart;

  const int NT = K >> 6, NI = NT >> 1;

  const int stgRow = w * 8 + (l >> 3);
  const int stgCol = ((l & 7) ^ (l >> 3)) * 8;

  const int xa = (r16 & 7) << 4;
  const int c0 = ((g * 16) ^ xa) >> 1;
  const int c1 = c0 ^ 32;
  const int aslot = wm ? 24576 : 8192;
  const int bslot = ((wn >> 1) ? 16384 : 0) + (wn & 1) * 4096;
  const ushort* pA0b0 = lds + aslot + r16 * 64 + c0;
  const ushort* pA1b0 = lds + aslot + r16 * 64 + c1;
  const ushort* pA0b1 = pA0b0 + 32768;
  const ushort* pA1b1 = pA1b0 + 32768;
  const ushort* pB0b0 = lds + bslot + r16 * 64 + c0;
  const ushort* pB1b0 = lds + bslot + r16 * 64 + c1;
  const ushort* pB0b1 = pB0b0 + 32768;
  const ushort* pB1b1 = pB1b0 + 32768;

  f32x4 acc[8][4];
#pragma unroll
  for (int i = 0; i < 8; i++)
#pragma unroll
    for (int j = 0; j < 4; j++) acc[i][j] = (f32x4){0, 0, 0, 0};

  auto stageA = [&](int slot, int tile, int hf) {
    ushort* dst = lds + ((tile & 1) * 32768 + slot * 8192 + w * 512);
    const ushort* src =
        Ag + (size_t)(hf * 128 + stgRow) * lda + tile * 64 + stgCol;
    gload16(src, dst);
    gload16(src + (size_t)64 * lda, dst + 4096);
  };
  auto stageB = [&](int slot, int tile, int hf) {
    ushort* dst = lds + ((tile & 1) * 32768 + slot * 8192 + w * 512);
    const ushort* src =
        Bg + (size_t)(hf * 128 + stgRow) * ldb + tile * 64 + stgCol;
    gload16(src, dst);
    gload16(src + (size_t)64 * ldb, dst + 4096);
  };

  stageB(0, 0, 0);
  stageB(2, 0, 1);
  stageA(1, 0, 0);
  stageA(3, 0, 1);
  stageB(0, 1, 0);
  stageB(2, 1, 1);
  asm volatile("s_waitcnt vmcnt(4)" ::: "memory");
  __builtin_amdgcn_s_barrier();

  bf16x8 A_[8], Blo[4], Bhi[4];

  for (int i = 0; i < NI; ++i) {
    const int ta = 2 * i, tb = 2 * i + 1;
    const bool st = (ta + 2 < NT);
    RD_A(pA0b0, pA1b0, 0);
    RD_B(Blo, pB0b0, pB1b0, 0);
    stageA(1, tb, 0);
    asm volatile("s_waitcnt lgkmcnt(8)" ::: "memory");
    PHASE_MID; QUAD(A_, Blo, 0, 0); PHASE_CLOSE;
    RD_B(Bhi, pB0b0, pB1b0, 2);
    stageA(3, tb, 1);
    PHASE_MID; QUAD(A_, Bhi, 0, 2); PHASE_CLOSE;
    RD_A(pA0b0, pA1b0, 4);
    if (st) stageB(0, ta + 2, 0);
    PHASE_MID; QUAD(A_, Bhi, 4, 2); PHASE_CLOSE;
    if (st) stageB(2, ta + 2, 1);
    PHASE_MID; QUAD(A_, Blo, 4, 0);
    __builtin_amdgcn_s_setprio(0);
    __builtin_amdgcn_sched_barrier(0);
    if (st) {
      asm volatile("s_waitcnt vmcnt(4)" ::: "memory");
    } else {
      asm volatile("s_waitcnt vmcnt(0)" ::: "memory");
    }
    __builtin_amdgcn_s_barrier();
    RD_A(pA0b1, pA1b1, 0);
    RD_B(Blo, pB0b1, pB1b1, 0);
    if (st) stageA(1, ta + 2, 0);
    asm volatile("s_waitcnt lgkmcnt(8)" ::: "memory");
    PHASE_MID; QUAD(A_, Blo, 0, 0); PHASE_CLOSE;
    RD_B(Bhi, pB0b1, pB1b1, 2);
    if (st) stageA(3, ta + 2, 1);
    PHASE_MID; QUAD(A_, Bhi, 0, 2); PHASE_CLOSE;
    RD_A(pA0b1, pA1b1, 4);
    if (st) stageB(0, tb + 2, 0);
    PHASE_MID; QUAD(A_, Bhi, 4, 2); PHASE_CLOSE;
    if (st) stageB(2, tb + 2, 1);
    PHASE_MID; QUAD(A_, Blo, 4, 0);
    __builtin_amdgcn_s_setprio(0);
    __builtin_amdgcn_sched_barrier(0);
    asm volatile("s_waitcnt vmcnt(4)" ::: "memory");
    __builtin_amdgcn_s_barrier();
  }

  if constexpr (EPI == EPI_PART) {
#pragma unroll
    for (int mf = 0; mf < 8; mf++)
#pragma unroll
      for (int nf = 0; nf < 4; nf++) {
        const int n = n0 + wn * 64 + nf * 16 + r16;
#pragma unroll
        for (int reg = 0; reg < 4; reg++) {
          const int m = m0 + wm * 128 + mf * 16 + g * 4 + reg;
          outbz[(size_t)m * ldc + n] = f2bf(acc[mf][nf][reg]);
        }
      }
  } else {  // EPI_SILU2
#pragma unroll
    for (int mf = 0; mf < 8; mf++)
#pragma unroll
      for (int p = 0; p < 2; p++) {
        const int L = (n0 >> 1) + wn * 32 + p * 16 + r16;
        const float bb1 = b1v[L], bb3 = b3v[L];
#pragma unroll
        for (int reg = 0; reg < 4; reg++) {
          const int m = m0 + wm * 128 + mf * 16 + g * 4 + reg;
          float h1 = acc[mf][2 * p][reg] + bb1;
          float h3 = acc[mf][2 * p + 1][reg] + bb3;
          float sv = h1 / (1.f + __expf(-h1));
          outbz[(size_t)m * ldc + L] = f2bf(sv * h3);
        }
      }
  }
}

// ---------------- fused QKV reduce + bias + RoPE (1 row / block) -----------
__global__ __launch_bounds__(384) void reduceQ_rope_k(
    const ushort* __restrict__ part, const float* __restrict__ bias,
    const float* __restrict__ cs, const float* __restrict__ sn,
    ushort* __restrict__ qkv) {
  __shared__ float row[3072];
  const int r = blockIdx.x;
  const int col = threadIdx.x * 8;
  const long long ps = (long long)S_LEN * 3072;
  float s[8];
#pragma unroll
  for (int j = 0; j < 8; j++) s[j] = bias[col + j];
#pragma unroll
  for (int z = 0; z < 2; z++) {
    bf16x8 v = *(const bf16x8*)(part + z * ps + (size_t)r * 3072 + col);
#pragma unroll
    for (int j = 0; j < 8; j++) s[j] += bf2f((ushort)v[j]);
  }
#pragma unroll
  for (int j = 0; j < 8; j++) row[col + j] = s[j];
  __syncthreads();
  ushort o[8];
  if (col < 2560) {
    const float* c = cs + r * HD + (col & 63);
    const float* si = sn + r * HD + (col & 63);
    const float sgn = (col & 32) ? 1.f : -1.f;
    const int pc = col ^ 32;
#pragma unroll
    for (int j = 0; j < 8; j++)
      o[j] = f2bf(s[j] * c[j] + sgn * row[pc + j] * si[j]);
  } else {
#pragma unroll
    for (int j = 0; j < 8; j++) o[j] = f2bf(s[j]);
  }
  bf16x8 rr;
#pragma unroll
  for (int j = 0; j < 8; j++) rr[j] = (short)o[j];
  *(bf16x8*)(qkv + (size_t)r * 3072 + col) = rr;
}

// ------- fused O-proj reduce + bias + resid -> out(f32) + RMSNorm -> x2 ----
__global__ __launch_bounds__(256) void reduceO_rms_k(
    const ushort* __restrict__ part, const float* __restrict__ bias,
    const float* __restrict__ resid, const float* __restrict__ lnw,
    float* __restrict__ outf, ushort* __restrict__ x2) {
  const int r = blockIdx.x;
  const int tid = threadIdx.x;
  const int col = tid * 8;
  const long long ps = (long long)S_LEN * DMODEL;
  float s[8];
#pragma unroll
  for (int j = 0; j < 8; j++) s[j] = bias[col + j] + resid[(size_t)r * DMODEL + col + j];
#pragma unroll
  for (int z = 0; z < 4; z++) {
    bf16x8 v = *(const bf16x8*)(part + z * ps + (size_t)r * DMODEL + col);
#pragma unroll
    for (int j = 0; j < 8; j++) s[j] += bf2f((ushort)v[j]);
  }
  float ss = 0.f;
#pragma unroll
  for (int j = 0; j < 8; j++) ss += s[j] * s[j];
#pragma unroll
  for (int off = 32; off; off >>= 1) ss += __shfl_xor(ss, off, 64);
  __shared__ float red[4];
  if ((tid & 63) == 0) red[tid >> 6] = ss;
  f32x4 o0, o1;
#pragma unroll
  for (int j = 0; j < 4; j++) { o0[j] = s[j]; o1[j] = s[4 + j]; }
  *(f32x4*)(outf + (size_t)r * DMODEL + col) = o0;
  *(f32x4*)(outf + (size_t)r * DMODEL + col + 4) = o1;
  __syncthreads();
  float tot = red[0] + red[1] + red[2] + red[3];
  float inv = rsqrtf(tot * (1.f / DMODEL) + 1e-5f);
  bf16x8 rr;
#pragma unroll
  for (int j = 0; j < 8; j++) rr[j] = (short)f2bf(lnw[col + j] * s[j] * inv);
  *(bf16x8*)(x2 + (size_t)r * DMODEL + col) = rr;
}

// ---------------- w2 reduce (f32 out + resid) ----------------
__global__ __launch_bounds__(256) void reduceW_k(
    const ushort* __restrict__ part, const float* __restrict__ bias,
    float* __restrict__ out) {
  long long i = (long long)(blockIdx.x * 256 + threadIdx.x) * 8;
  int col = (int)(i % DMODEL);
  const long long ps = (long long)S_LEN * DMODEL;
  float s[8];
#pragma unroll
  for (int j = 0; j < 8; j++) s[j] = bias[col + j] + out[i + j];
#pragma unroll
  for (int z = 0; z < 4; z++) {
    bf16x8 v = *(const bf16x8*)(part + z * ps + i);
#pragma unroll
    for (int j = 0; j < 8; j++) s[j] += bf2f((ushort)v[j]);
  }
#pragma unroll
  for (int j = 0; j < 8; j++) out[i + j] = s[j];
}

// ======== Flash attention (QBLK=64, 128 threads, 2 waves) + cvt blocks =====
__global__ __launch_bounds__(128, 3) void flash2_k(
    const ushort* __restrict__ qkv, ushort* __restrict__ att, int nFlash,
    int nCvtTasks, const float* __restrict__ wo, const float* __restrict__ w1,
    const float* __restrict__ w3, const float* __restrict__ w2s,
    ushort* __restrict__ cwA, ushort* __restrict__ cwB) {
  if ((int)blockIdx.x >= nFlash) {
    const int cb = blockIdx.x - nFlash;
    const int NC = gridDim.x - nFlash;
    const int i = threadIdx.x * 8;
    for (int t = cb; t < nCvtTasks; t += NC) {
      const float* src;
      ushort* dst;
      if (t < 2048) {
        src = wo + (size_t)t * DMODEL;
        dst = cwB + (size_t)t * DMODEL;
      } else if (t < 18432) {
        int r = t - 2048;
        int nb = r >> 8, i5 = r & 255;
        int wn = i5 >> 6, nf = (i5 >> 4) & 3, e = i5 & 15;
        int L = nb * 128 + wn * 32 + (nf >> 1) * 16 + e;
        src = ((nf & 1) ? w3 : w1) + (size_t)L * DMODEL;
        dst = cwA + (size_t)r * DMODEL;
      } else {
        int r = t - 18432;
        src = w2s + (size_t)r * 2048;
        dst = cwB + (size_t)2048 * DMODEL + (size_t)r * 2048;
      }
      cvt_row8(src, dst, i);
      cvt_row8(src, dst, i + 1024);
    }
    return;
  }
  const int bid = blockIdx.x;
  const int head = (bid >> 5) & 31;
  const int rmap = bid & 31;
  const int qb = (bid & 512) ? (31 - rmap) : rmap;  // causal balance
  const int kvh = head >> 2;
  const int tid = threadIdx.x;
  const int w = tid >> 6, l = tid & 63;
  const int h = l >> 5, q31 = l & 31;
  const int qw = qb * 64 + w * 32;
  const int qrow = qw + q31;

  __shared__ __align__(16) ushort lds[2][8192];

  bf16x8 qreg[4];
  {
    const ushort* qp = qkv + (size_t)qrow * 3072 + head * HD;
#pragma unroll
    for (int s = 0; s < 4; s++)
      qreg[s] = *(const bf16x8*)(qp + s * 16 + h * 8);
  }

  f32x16 oacc[2];
#pragma unroll
  for (int i = 0; i < 16; i++) { oacc[0][i] = 0.f; oacc[1][i] = 0.f; }
  float mreg = -1e30f, lsum = 0.f;

  const int nt = qb + 1;

  const int skv = tid >> 1;
  const int sc4 = (tid & 1) * 4;
  const int vkv = tid & 63;
  const int vd0 = (tid >> 6) * 32;

  const ushort* kg_base = qkv + DMODEL + kvh * HD;

  bf16x8 kr[4], vr[4];
  auto loadTile = [&](int jb) {
    const ushort* kg = kg_base + (size_t)jb * 64 * 3072;
#pragma unroll
    for (int c = 0; c < 4; c++)
      kr[c] = *(const bf16x8*)(kg + (size_t)skv * 3072 + (sc4 + c) * 8);
    const ushort* vg = kg + 512;
#pragma unroll
    for (int c = 0; c < 4; c++)
      vr[c] = *(const bf16x8*)(vg + (size_t)vkv * 3072 + vd0 + c * 8);
  };
  auto writeTile = [&](int b) {
    ushort* kb = lds[b];
#pragma unroll
    for (int c = 0; c < 4; c++)
      *(bf16x8*)(kb + skv * 64 + (((sc4 + c) ^ (skv & 7)) * 8)) = kr[c];
    ushort* vb = lds[b] + 4096;
#pragma unroll
    for (int c = 0; c < 4; c++)
#pragma unroll
      for (int i = 0; i < 8; i++) {
        int d = vd0 + c * 8 + i;
        vb[d * 64 + (((vkv >> 3) ^ (d & 7)) * 8) + (vkv & 7)] = (ushort)vr[c][i];
      }
  };

  loadTile(0);
  for (int jb = 0; jb < nt; ++jb) {
    const int b = jb & 1;
    writeTile(b);
    __syncthreads();
    if (jb + 1 < nt) loadTile(jb + 1);

    if (jb * 64 <= qw + 31) {
      const ushort* Kb = lds[b];
      const ushort* Vb = lds[b] + 4096;

      f32x16 sacc[2];
#pragma unroll
      for (int i = 0; i < 16; i++) { sacc[0][i] = 0.f; sacc[1][i] = 0.f; }
#pragma unroll
      for (int c = 0; c < 2; c++) {
        const int kvr = c * 32 + q31;
        const ushort* kp = Kb + kvr * 64;
        const int kx = kvr & 7;
#pragma unroll
        for (int s = 0; s < 4; s++) {
          bf16x8 kf = *(const bf16x8*)(kp + ((2 * s + h) ^ kx) * 8);
          sacc[c] = MFMA32(kf, qreg[s], sacc[c]);
        }
      }

      const bool diag = (jb * 64 + 63 > qw);
      if (diag) {
#pragma unroll
        for (int c = 0; c < 2; c++)
#pragma unroll
          for (int rg = 0; rg < 16; rg++) {
            int kvg = jb * 64 + c * 32 + (rg & 3) + 8 * (rg >> 2) + 4 * h;
            if (kvg > qrow) sacc[c][rg] = -1e30f;
          }
      }
      float tmax = sacc[0][0];
#pragma unroll
      for (int rg = 1; rg < 16; rg++) tmax = fmaxf(tmax, sacc[0][rg]);
#pragma unroll
      for (int rg = 0; rg < 16; rg++) tmax = fmaxf(tmax, sacc[1][rg]);
      tmax = fmaxf(tmax, __shfl_xor(tmax, 32));
      const float mn = fmaxf(mreg, tmax);
      const float resc = __expf((mreg - mn) * 0.125f);
      mreg = mn;
      float rsum = 0.f;
#pragma unroll
      for (int c = 0; c < 2; c++)
#pragma unroll
        for (int rg = 0; rg < 16; rg++) {
          float pv = __expf((sacc[c][rg] - mn) * 0.125f);
          sacc[c][rg] = pv;
          rsum += pv;
        }
      rsum += __shfl_xor(rsum, 32);
      lsum = lsum * resc + rsum;
      oacc[0] *= resc;
      oacc[1] *= resc;

      unsigned pw_[2][4][2];
#pragma unroll
      for (int c = 0; c < 2; c++)
#pragma unroll
        for (int rr = 0; rr < 4; rr++) {
          pw_[c][rr][0] = cvtpk(sacc[c][4 * rr + 0], sacc[c][4 * rr + 1]);
          pw_[c][rr][1] = cvtpk(sacc[c][4 * rr + 2], sacc[c][4 * rr + 3]);
        }

#pragma unroll
      for (int s = 0; s < 4; s++) {
        const int c = s >> 1, base = (s & 1) * 2;
        unsigned k0 = h ? pw_[c][base + 1][0] : pw_[c][base][0];
        unsigned k1 = h ? pw_[c][base + 1][1] : pw_[c][base][1];
        unsigned s0 = h ? pw_[c][base][0] : pw_[c][base + 1][0];
        unsigned s1 = h ? pw_[c][base][1] : pw_[c][base + 1][1];
        unsigned t0 = __shfl_xor(s0, 32);
        unsigned t1 = __shfl_xor(s1, 32);
        union { unsigned u[4]; bf16x8 v; } pf;
        pf.u[0] = h ? t0 : k0;
        pf.u[1] = h ? t1 : k1;
        pf.u[2] = h ? k0 : t0;
        pf.u[3] = h ? k1 : t1;
#pragma unroll
        for (int dt = 0; dt < 2; dt++) {
          const int d = dt * 32 + q31;
          bf16x8 vf =
              *(const bf16x8*)(Vb + d * 64 + ((2 * s + h) ^ (d & 7)) * 8);
          oacc[dt] = MFMA32(vf, pf.v, oacc[dt]);
        }
      }
    }
  }

  const float inv = 1.f / lsum;
  ushort* op = att + (size_t)qrow * DMODEL + head * HD;
#pragma unroll
  for (int dt = 0; dt < 2; dt++)
#pragma unroll
    for (int rr = 0; rr < 4; rr++) {
      const int d0 = dt * 32 + 8 * rr + 4 * h;
      unsigned lo = cvtpk(oacc[dt][4 * rr + 0] * inv, oacc[dt][4 * rr + 1] * inv);
      unsigned hi = cvtpk(oacc[dt][4 * rr + 2] * inv, oacc[dt][4 * rr + 3] * inv);
      uint2 v2;
      v2.x = lo;
      v2.y = hi;
      *(uint2*)(op + d0) = v2;
    }
}

extern "C" void kernel_launch(void* const* d_in, const int* in_sizes, int n_in,
                              void* d_out, int out_size, void* d_ws,
                              size_t ws_size, hipStream_t stream) {
  (void)in_sizes; (void)n_in; (void)out_size;
  const float* hidden = (const float*)d_in[0];
  const float* cosb = (const float*)d_in[1];
  const float* sinb = (const float*)d_in[2];
  const float* wq = (const float*)d_in[4];
  const float* bq = (const float*)d_in[5];
  const float* wk = (const float*)d_in[6];
  const float* bk = (const float*)d_in[7];
  const float* wv = (const float*)d_in[8];
  const float* bv = (const float*)d_in[9];
  const float* wo = (const float*)d_in[10];
  const float* bo = (const float*)d_in[11];
  const float* ln1 = (const float*)d_in[12];
  const float* ln2 = (const float*)d_in[13];
  const float* w1 = (const float*)d_in[16];
  const float* b1 = (const float*)d_in[17];
  const float* w2 = (const float*)d_in[18];
  const float* b2 = (const float*)d_in[19];
  const float* w3 = (const float*)d_in[20];
  const float* b3 = (const float*)d_in[21];
  float* out = (float*)d_out;

  char* base = (char*)d_ws;
  char* ws = base;
  ushort* x1 = (ushort*)ws;   ws += (size_t)S_LEN * DMODEL * 2;
  ushort* qkv = (ushort*)ws;  ws += (size_t)S_LEN * 3072 * 2;
  ushort* att = (ushort*)ws;  ws += (size_t)S_LEN * DMODEL * 2;
  ushort* x2 = (ushort*)ws;   ws += (size_t)S_LEN * DMODEL * 2;
  ushort* hbuf = (ushort*)ws; ws += (size_t)S_LEN * FFN_DIM * 2;
  ushort* cwA = (ushort*)ws;  ws += (size_t)2 * FFN_DIM * DMODEL * 2;
  float* bqkv = (float*)ws;   ws += 4096 * 4;
  ushort* cwB = (ushort*)ws;
  const size_t cwB_bytes = (size_t)(2048 + 8192) * DMODEL * 2;
  const bool bigws = ((size_t)(ws - base) + cwB_bytes) <= ws_size;

  ushort* partQ = att;   // 2x12.6MB over att+x2+hbuf (dead pre-attention)
  ushort* partO = hbuf;  // 4x8.4MB == hbuf (dead pre-FFN); x2 live
  ushort* partW = x1;    // 4x8.4MB over x1+qkv+att+x2 (dead at w2)

  // 1. rmsnorm1 + cvt_qkv + bias3 (block-specialized)
  pre_k<<<5132, 256, 0, stream>>>(hidden, ln1, x1, wq, wk, wv, cwA, bq, bk, bv,
                                  bqkv);

  // 2. QKV GEMM split-K=2 -> fused reduce+bias+RoPE -> qkv
  gemm256<EPI_PART><<<dim3(8, 12, 2), 512, 0, stream>>>(
      x1, DMODEL, cwA, DMODEL, nullptr, nullptr, partQ, 3072, 1024, 1024,
      (long long)S_LEN * 3072);
  reduceQ_rope_k<<<S_LEN, 384, 0, stream>>>(partQ, bqkv, cosb, sinb, qkv);

  const ushort *Bo, *B13, *B2;
  if (bigws) {
    // 3. Flash attention (1024 blocks) + 512 cvt blocks
    flash2_k<<<1024 + 512, 128, 0, stream>>>(qkv, att, 1024, 26624, wo, w1, w3,
                                             w2, cwA, cwB);
    Bo = cwB;
    B13 = cwA;
    B2 = cwB + (size_t)2048 * DMODEL;
  } else {
    flash2_k<<<1024, 128, 0, stream>>>(qkv, att, 1024, 0, wo, w1, w3, w2, cwA,
                                       cwA);
    Bo = cwA;
    B13 = cwA;
    B2 = cwA;
  }

  // 4. O-proj split-K=4 -> fused reduce+resid -> out(f32) + RMSNorm2 -> x2
  if (!bigws) cvt_k<<<(2048 * 2048) / 2048, 256, 0, stream>>>(wo, (ushort*)Bo);
  gemm256<EPI_PART><<<dim3(8, 8, 4), 512, 0, stream>>>(
      att, DMODEL, Bo, DMODEL, nullptr, nullptr, partO, DMODEL, 512, 512,
      (long long)S_LEN * DMODEL);
  reduceO_rms_k<<<S_LEN, 256, 0, stream>>>(partO, bo, hidden, ln2, out, x2);

  // 5. fused w1+w3 GEMM -> hbuf = silu(h1)*h3
  if (!bigws) cvt_w13_k<<<2 * FFN_DIM, 256, 0, stream>>>(w1, w3, (ushort*)B13);
  gemm256<EPI_SILU2><<<dim3(8, 64), 512, 0, stream>>>(
      x2, DMODEL, B13, DMODEL, b1, b3, hbuf, FFN_DIM, DMODEL, 0, 0);

  // 6. w2 split-K=4 -> reduce (+b2 + out resid) -> out
  if (!bigws) cvt_k<<<(DMODEL * FFN_DIM) / 2048, 256, 0, stream>>>(w2, (ushort*)B2);
  gemm256<EPI_PART><<<dim3(8, 8, 4), 512, 0, stream>>>(
      hbuf, FFN_DIM, B2, FFN_DIM, nullptr, nullptr, partW, DMODEL, 2048, 2048,
      (long long)S_LEN * DMODEL);
  reduceW_k<<<(S_LEN * DMODEL) / 2048, 256, 0, stream>>>(partW, b2, out);
}